// Round 9
// baseline (394.111 us; speedup 1.0000x reference)
//
#include <hip/hip_runtime.h>
#include <hip/hip_cooperative_groups.h>
#include <stdint.h>

namespace cg = cooperative_groups;

// ---------------------------------------------------------------------------
// BNNLinear: out = BatchNorm( sign(x) @ sign(W)^T )
//   x: [M, K] f32, W: [N, K] f32, gamma/beta: [N] f32  ->  out: [M, N] f32
//
// Round 9 == round 8 with the compile fix (M/N/K must be non-const so &M
// fits the void* kernel-args array). Design:
// GEMM core = R6 bit-exact (BK=128, measured-zero swizzle, 128 combined
// regs, 4 blk/CU). Fused cooperative kernel, 1024 blocks x 1 tile =
// exactly co-resident at 4 blk/CU:
//   phase 0: zero stats + binarize x,W -> i8 (grid-stride)
//   grid.sync()
//   phase 1: R6 K-loop; stats atomics; acc stays in AGPRs (NO raw C store)
//   grid.sync()
//   phase 2: normalize from registers, single f32 C store
// Deletes the 32 MB i16 write + 32 MB read + 2 launches vs R6.
// Fallback: full R6 pipeline if cooperative validation fails.
// ---------------------------------------------------------------------------

typedef int int32x4 __attribute__((ext_vector_type(4)));

#define BM 128
#define BN 128
#define BKI 128  // i8 k-bytes per LDS tile
#define EPS_BN 1e-5f

__device__ __forceinline__ void load16_lds(const void* g, void* l) {
  // 16B per lane, LDS dest = wave-uniform base + lane*16 (linear, no scatter)
  __builtin_amdgcn_global_load_lds(
      (const __attribute__((address_space(1))) void*)g,
      (__attribute__((address_space(3))) void*)l,
      16, 0, 0);
}

__device__ __forceinline__ char sgn(float v) {
  return v > 0.f ? (char)1 : (v < 0.f ? (char)-1 : (char)0);
}

// ---- R6 GEMM K-loop core (i8, BK=128, zero-conflict swizzle) --------------
// LDS swizzle: row r's 16B chunk slot c holds global k-chunk (c ^ (r&7));
// XOR applied on the GLOBAL source address (DMA dest stays linear); readers
// apply the same XOR. Measured (R5/R6): SQ_LDS_BANK_CONFLICT == 0.
__device__ __forceinline__ void gemm_core(
    const char* __restrict__ A, const char* __restrict__ Bt,
    int rowBlock, int colBlock, int K, char* sA, char* sB,
    int wave, int lane, int32x4 acc[4][4]) {
  const int laneRow = lane >> 3;                 // 0..7 (== row & 7)
  const int c       = lane & 7;                  // chunk slot 0..7
  const int swz     = ((c ^ laneRow) & 7) * 16;  // global k-byte offset

  const char* Ag = A  + (size_t)(rowBlock + wave * 32 + laneRow) * K + swz;
  const char* Bg = Bt + (size_t)(colBlock + wave * 32 + laneRow) * K + swz;
  char* sAw = &sA[(wave * 32) * BKI];
  char* sBw = &sB[(wave * 32) * BKI];

  const int f    = lane & 15;
  const int quad = lane >> 4;
  const int wr = (wave >> 1) * 64;
  const int wc = (wave & 1) * 64;
  const int f7 = f & 7;

  for (int k0 = 0; k0 < K; k0 += BKI) {
    __syncthreads();  // prior ds_reads complete before overwrite
#pragma unroll
    for (int i = 0; i < 4; ++i) {
      load16_lds(Ag + k0 + (size_t)(i * 8) * K, sAw + i * 8 * BKI);
      load16_lds(Bg + k0 + (size_t)(i * 8) * K, sBw + i * 8 * BKI);
    }
    __syncthreads();  // vmcnt drain -> staging visible

#pragma unroll
    for (int s = 0; s < 2; ++s) {  // two K=64 sub-steps
      const int chunk = ((s * 4 + quad) ^ f7) * 16;
      int32x4 af[4], bfr[4];
#pragma unroll
      for (int mi = 0; mi < 4; ++mi)
        af[mi] = *reinterpret_cast<const int32x4*>(
            &sA[(wr + mi * 16 + f) * BKI + chunk]);
#pragma unroll
      for (int ni = 0; ni < 4; ++ni)
        bfr[ni] = *reinterpret_cast<const int32x4*>(
            &sB[(wc + ni * 16 + f) * BKI + chunk]);
#pragma unroll
      for (int mi = 0; mi < 4; ++mi)
#pragma unroll
        for (int ni = 0; ni < 4; ++ni)
          acc[mi][ni] = __builtin_amdgcn_mfma_i32_16x16x64_i8(
              af[mi], bfr[ni], acc[mi][ni], 0, 0, 0);
    }
  }
}

// ---- fused cooperative kernel ---------------------------------------------
__global__ __launch_bounds__(256, 4) void bnn_fused_kernel(
    const float* __restrict__ x, const float* __restrict__ w,
    const float* __restrict__ gamma, const float* __restrict__ beta,
    char* __restrict__ Abin, char* __restrict__ Bbin,
    float* __restrict__ colSum, float* __restrict__ colSq,
    float* __restrict__ C, int M, int N, int K) {
  cg::grid_group grid = cg::this_grid();

  const int tid  = threadIdx.x;
  const int gtid = blockIdx.x * blockDim.x + tid;
  const int gstride = gridDim.x * blockDim.x;

  // ---- phase 0: zero stats + binarize ------------------------------------
  if (gtid < 2 * N) colSum[gtid] = 0.f;  // colSum|colSq contiguous
  {
    const int nx4 = (M * K) / 4;
    const int ntot = nx4 + (N * K) / 4;
    for (int idx = gtid; idx < ntot; idx += gstride) {
      const float4* src;
      char* dst;
      int i;
      if (idx < nx4) {
        src = reinterpret_cast<const float4*>(x); dst = Abin; i = idx;
      } else {
        src = reinterpret_cast<const float4*>(w); dst = Bbin; i = idx - nx4;
      }
      float4 v = src[i];
      char4 o;
      o.x = sgn(v.x); o.y = sgn(v.y); o.z = sgn(v.z); o.w = sgn(v.w);
      reinterpret_cast<char4*>(dst)[i] = o;
    }
  }

  grid.sync();  // binarized data + zeroed stats visible device-wide

  // ---- phase 1: GEMM tile, acc in AGPRs ----------------------------------
  __shared__ __align__(16) char sA[BM * BKI];  // 16 KiB
  __shared__ __align__(16) char sB[BN * BKI];  // 16 KiB

  const int wave = tid >> 6;
  const int lane = tid & 63;
  const int nby = M / BM;  // consecutive blocks share B panel (L2)
  const int rowBlock = (blockIdx.x % nby) * BM;
  const int colBlock = (blockIdx.x / nby) * BN;

  int32x4 acc[4][4] = {};
  gemm_core(Abin, Bbin, rowBlock, colBlock, K, sA, sB, wave, lane, acc);

  // stats: C/D layout col = lane&15, row = quad*4 + reg (verified)
  const int f    = lane & 15;
  const int quad = lane >> 4;
  const int wr = (wave >> 1) * 64;
  const int wc = (wave & 1) * 64;
#pragma unroll
  for (int ni = 0; ni < 4; ++ni) {
    const int col = colBlock + wc + ni * 16 + f;
    float s = 0.f, sq = 0.f;
#pragma unroll
    for (int mi = 0; mi < 4; ++mi)
#pragma unroll
      for (int r = 0; r < 4; ++r) {
        const float fv = (float)acc[mi][ni][r];
        s += fv;
        sq += fv * fv;
      }
    s  += __shfl_xor(s, 16);  s  += __shfl_xor(s, 32);
    sq += __shfl_xor(sq, 16); sq += __shfl_xor(sq, 32);
    if (quad == 0) {
      atomicAdd(&colSum[col], s);   // integer-valued: exact in fp32
      atomicAdd(&colSq[col], sq);
    }
  }

  grid.sync();  // all stats complete device-wide

  // ---- phase 2: normalize from registers, single f32 store ---------------
  const float invM = 1.0f / (float)M;
#pragma unroll
  for (int ni = 0; ni < 4; ++ni) {
    const int col = colBlock + wc + ni * 16 + f;
    const float mean = colSum[col] * invM;
    const float var  = colSq[col] * invM - mean * mean;  // biased
    const float sc   = gamma[col] * rsqrtf(var + EPS_BN);
    const float sh   = beta[col] - mean * sc;
#pragma unroll
    for (int mi = 0; mi < 4; ++mi) {
      float* Cp = C + (size_t)(rowBlock + wr + mi * 16 + quad * 4) * N + col;
#pragma unroll
      for (int r = 0; r < 4; ++r)
        Cp[(size_t)r * N] = (float)acc[mi][ni][r] * sc + sh;
    }
  }
}

// ---- fallback pipeline (R6, proven 179.5 us) ------------------------------
__global__ void binarize_kernel(const float* __restrict__ x,
                                const float* __restrict__ w,
                                char* __restrict__ Ab, char* __restrict__ Bb,
                                float* __restrict__ stats, int nx4, int ntot4,
                                int n2) {
  int idx = blockIdx.x * blockDim.x + threadIdx.x;
  if (idx < n2) stats[idx] = 0.f;
  if (idx >= ntot4) return;
  const float4* src;
  char* dst;
  int i;
  if (idx < nx4) {
    src = reinterpret_cast<const float4*>(x); dst = Ab; i = idx;
  } else {
    src = reinterpret_cast<const float4*>(w); dst = Bb; i = idx - nx4;
  }
  float4 v = src[i];
  char4 o;
  o.x = sgn(v.x); o.y = sgn(v.y); o.z = sgn(v.z); o.w = sgn(v.w);
  reinterpret_cast<char4*>(dst)[i] = o;
}

__global__ __launch_bounds__(256, 4) void gemm_i8_kernel(
    const char* __restrict__ A, const char* __restrict__ Bt,
    short* __restrict__ Craw, float* __restrict__ colSum,
    float* __restrict__ colSq, int M, int N, int K) {
  __shared__ __align__(16) char sA[BM * BKI];
  __shared__ __align__(16) char sB[BN * BKI];
  const int tid = threadIdx.x;
  const int wave = tid >> 6, lane = tid & 63;
  const int nby = M / BM;
  const int rowBlock = (blockIdx.x % nby) * BM;
  const int colBlock = (blockIdx.x / nby) * BN;

  int32x4 acc[4][4] = {};
  gemm_core(A, Bt, rowBlock, colBlock, K, sA, sB, wave, lane, acc);

  const int f = lane & 15, quad = lane >> 4;
  const int wr = (wave >> 1) * 64, wc = (wave & 1) * 64;
#pragma unroll
  for (int ni = 0; ni < 4; ++ni) {
    const int col = colBlock + wc + ni * 16 + f;
    float s = 0.f, sq = 0.f;
#pragma unroll
    for (int mi = 0; mi < 4; ++mi) {
      short* Cp = Craw + (size_t)(rowBlock + wr + mi * 16 + quad * 4) * N + col;
#pragma unroll
      for (int r = 0; r < 4; ++r) {
        const int v = acc[mi][ni][r];
        Cp[(size_t)r * N] = (short)v;
        const float fv = (float)v;
        s += fv;
        sq += fv * fv;
      }
    }
    s  += __shfl_xor(s, 16);  s  += __shfl_xor(s, 32);
    sq += __shfl_xor(sq, 16); sq += __shfl_xor(sq, 32);
    if (quad == 0) {
      atomicAdd(&colSum[col], s);
      atomicAdd(&colSq[col], sq);
    }
  }
}

__global__ void norm_kernel(const short* __restrict__ Craw,
                            float* __restrict__ C,
                            const float* __restrict__ colSum,
                            const float* __restrict__ colSq,
                            const float* __restrict__ gamma,
                            const float* __restrict__ beta, int ncol4mask,
                            int ncol4shift, int halfRows, float invM) {
  const int idx = blockIdx.x * blockDim.x + threadIdx.x;
  const int c4  = idx & ncol4mask;
  const int row = idx >> ncol4shift;
  const int col = c4 * 4;
  const int ncol4 = ncol4mask + 1;

  const float4 sm = *reinterpret_cast<const float4*>(&colSum[col]);
  const float4 sv = *reinterpret_cast<const float4*>(&colSq[col]);
  const float4 g  = *reinterpret_cast<const float4*>(&gamma[col]);
  const float4 b  = *reinterpret_cast<const float4*>(&beta[col]);

  float4 sc, sh;
  {
    float m, vv;
    m = sm.x * invM; vv = sv.x * invM - m * m;
    sc.x = g.x * rsqrtf(vv + EPS_BN); sh.x = b.x - m * sc.x;
    m = sm.y * invM; vv = sv.y * invM - m * m;
    sc.y = g.y * rsqrtf(vv + EPS_BN); sh.y = b.y - m * sc.y;
    m = sm.z * invM; vv = sv.z * invM - m * m;
    sc.z = g.z * rsqrtf(vv + EPS_BN); sh.z = b.z - m * sc.z;
    m = sm.w * invM; vv = sv.w * invM - m * m;
    sc.w = g.w * rsqrtf(vv + EPS_BN); sh.w = b.w - m * sc.w;
  }

#pragma unroll
  for (int h = 0; h < 2; ++h) {
    const size_t e = (size_t)(row + h * halfRows) * ncol4 + c4;
    const short4 rv = reinterpret_cast<const short4*>(Craw)[e];
    float4 o;
    o.x = (float)rv.x * sc.x + sh.x;
    o.y = (float)rv.y * sc.y + sh.y;
    o.z = (float)rv.z * sc.z + sh.z;
    o.w = (float)rv.w * sc.w + sh.w;
    reinterpret_cast<float4*>(C)[e] = o;
  }
}

// ---------------------------------------------------------------------------
extern "C" void kernel_launch(void* const* d_in, const int* in_sizes, int n_in,
                              void* d_out, int out_size, void* d_ws,
                              size_t ws_size, hipStream_t stream) {
  const float* x     = (const float*)d_in[0];
  const float* w     = (const float*)d_in[1];
  const float* gamma = (const float*)d_in[2];
  const float* beta  = (const float*)d_in[3];
  float* C = (float*)d_out;

  int N = in_sizes[2];      // OUT  (non-const: &N feeds void* args array)
  int K = in_sizes[1] / N;  // IN
  int M = in_sizes[0] / K;  // batch

  // workspace: [A i8 M*K][B i8 N*K][Craw i16 M*N (fallback only)][stats 2N]
  char* ws = (char*)d_ws;
  char* Abin = ws;
  char* Bbin = ws + (size_t)M * K;
  short* Craw = (short*)(ws + (size_t)M * K + (size_t)N * K);
  float* stats = (float*)((char*)Craw + (size_t)M * N * sizeof(short));
  float* colSum = stats;
  float* colSq  = stats + N;

  const int nTiles = (M / BM) * (N / BN);  // 1024 = 256 CUs x 4 blocks

  void* args[] = {&x, &w, &gamma, &beta, &Abin, &Bbin,
                  &colSum, &colSq, &C, &M, &N, &K};
  hipError_t err = hipLaunchCooperativeKernel(
      (const void*)bnn_fused_kernel, dim3(nTiles), dim3(256), args, 0, stream);

  if (err != hipSuccess) {
    // fallback: proven R6 pipeline
    (void)hipGetLastError();
    int nx4 = (M * K) / 4;
    int ntot4 = (M * K + N * K) / 4;
    binarize_kernel<<<(ntot4 + 255) / 256, 256, 0, stream>>>(
        x, w, Abin, Bbin, stats, nx4, ntot4, 2 * N);
    gemm_i8_kernel<<<nTiles, 256, 0, stream>>>(Abin, Bbin, Craw, colSum, colSq,
                                               M, N, K);
    int ncol4 = N / 4;
    int shift = 0;
    while ((1 << shift) < ncol4) ++shift;
    int total = (M / 2) * ncol4;
    norm_kernel<<<(total + 255) / 256, 256, 0, stream>>>(
        Craw, C, colSum, colSq, gamma, beta, ncol4 - 1, shift, M / 2,
        1.0f / (float)M);
  }
}